// Round 23
// baseline (370.222 us; speedup 1.0000x reference)
//
#include <hip/hip_runtime.h>
#include <hip/hip_fp16.h>
#include <math.h>

#define D_IN  512
#define D_HID 16
#define D_OUT 64
#define NBLK  256   // partition chunks
#define BKT   256   // nodes per bucket
#define CAP   12288 // fixed edge capacity per bucket (mean 8192, sigma~90)

// ---------------------------------------------------------------------------
// init global bucket cursors: gcur[b] = b*CAP
__global__ __launch_bounds__(512) void k_init(int* __restrict__ gcur, int NB) {
    int i = threadIdx.x;
    if (i < NB) gcur[i] = i * CAP;
}

// fused partition + split-K 2-row gemm1 in ONE dispatch:
//  blocks [0, NBLK)   : edge partition (4KB LDS histogram -> one global
//                       atomicAdd per (block,bucket) -> scatter packed)
//  blocks [NBLK, ...) : split-K gemm, TWO rows per 4-lane group (halves the
//                       per-row LDS read traffic -- the invariant limiter:
//                       r21/r22 showed 12 vs 21 waves/CU both ~135us).
//                       gb = blockIdx-NBLK; half = gb&1; rows (gb>>1)*128..+128,
//                       k in [half*256, half*256+256). fp16 partials ->
//                       bufAh (half 0) / bufBh (half 1); k_rssort sums+scales.
// Swizzle: store [k][c ^ ((k>>6)&3)], read [kk][c ^ part] (kk's 64-segment id
// == part) -> conflict-free (r22-verified). 2-row body = r13's v2 (44-52 VGPR,
// no cliff). DO NOT add launch_bounds min-waves / xa-batch / fp16-LDS /
// no-LDS: all hit compiler cliffs (r16,r17,r19,r20).
__global__ __launch_bounds__(256) void k_gp(const float* __restrict__ x,
                                            const float* __restrict__ W1,
                                            const int* __restrict__ src,
                                            const int* __restrict__ dst,
                                            int* __restrict__ gcur,
                                            unsigned int* __restrict__ packed,
                                            __half* __restrict__ m1hA,
                                            __half* __restrict__ m1hB,
                                            int E, int NB, int n) {
    __shared__ float4 w4s[256][4];  // 16 KiB (partition path aliases 4 KiB)
    int t = threadIdx.x;

    if (blockIdx.x < NBLK) {
        // ---------------- partition path ----------------
        int* h   = (int*)&w4s[0][0];
        int* cur = h + 512;
        for (int i = t; i < NB; i += 256) h[i] = 0;
        __syncthreads();
        int per = (E + NBLK - 1) / NBLK;
        int e0 = blockIdx.x * per, e1 = min(E, e0 + per);
        int nv = (e1 - e0) >> 2;
        const int4* d4 = (const int4*)(dst + e0);
        for (int i = t; i < nv; i += 256) {
            int4 v = d4[i];
            atomicAdd(&h[v.x >> 8], 1);
            atomicAdd(&h[v.y >> 8], 1);
            atomicAdd(&h[v.z >> 8], 1);
            atomicAdd(&h[v.w >> 8], 1);
        }
        for (int e = e0 + (nv << 2) + t; e < e1; e += 256)
            atomicAdd(&h[dst[e] >> 8], 1);
        __syncthreads();
        for (int i = t; i < NB; i += 256) {
            int c = h[i];
            cur[i] = c ? atomicAdd(&gcur[i], c) : 0;
        }
        __syncthreads();
        const int4* s4 = (const int4*)(src + e0);
        for (int i = t; i < nv; i += 256) {
            int4 sv = s4[i];
            int4 dv = d4[i];
#define PUT(ss, dd) { \
            int slot = atomicAdd(&cur[(dd) >> 8], 1); \
            packed[slot] = ((unsigned int)(ss) << 8) | (unsigned int)((dd) & 255); }
            PUT(sv.x, dv.x) PUT(sv.y, dv.y) PUT(sv.z, dv.z) PUT(sv.w, dv.w)
        }
        for (int e = e0 + (nv << 2) + t; e < e1; e += 256) {
            int d = dst[e];
            PUT(src[e], d)
        }
#undef PUT
        return;
    }

    // ---------------- split-K 2-row gemm path ----------------
    int gb   = blockIdx.x - NBLK;
    int half = gb & 1;
    const float4* Wh = (const float4*)(W1 + (size_t)half * 256 * D_HID);
    for (int i = t; i < 256 * 4; i += 256) {
        int k = i >> 2, c = i & 3;
        w4s[k][c ^ ((k >> 6) & 3)] = Wh[i];
    }
    __syncthreads();

    int group = t >> 2;
    int part  = t & 3;
    int r0 = (gb >> 1) * 128 + group * 2;
    int r1 = r0 + 1;
    if (r0 >= n) return;
    bool has1 = (r1 < n);

    const float4* xr0 = (const float4*)(x + (size_t)r0 * D_IN) + half * 64 + part * 16;
    const float4* xr1 = (const float4*)(x + (size_t)(has1 ? r1 : r0) * D_IN) + half * 64 + part * 16;

    float4 accA[4], accB[4];
#pragma unroll
    for (int c = 0; c < 4; c++) {
        accA[c] = make_float4(0.f, 0.f, 0.f, 0.f);
        accB[c] = make_float4(0.f, 0.f, 0.f, 0.f);
    }

#pragma unroll 4
    for (int m = 0; m < 16; m++) {
        float4 xa = xr0[m];
        float4 xb = xr1[m];
        int kb = part * 64 + m * 4;
#pragma unroll
        for (int u = 0; u < 4; u++) {
            int kk = kb + u;
            float xs_a = (u == 0) ? xa.x : (u == 1) ? xa.y : (u == 2) ? xa.z : xa.w;
            float xs_b = (u == 0) ? xb.x : (u == 1) ? xb.y : (u == 2) ? xb.z : xb.w;
#pragma unroll
            for (int c = 0; c < 4; c++) {
                float4 wv = w4s[kk][c ^ part];
                accA[c].x += xs_a * wv.x; accA[c].y += xs_a * wv.y;
                accA[c].z += xs_a * wv.z; accA[c].w += xs_a * wv.w;
                accB[c].x += xs_b * wv.x; accB[c].y += xs_b * wv.y;
                accB[c].z += xs_b * wv.z; accB[c].w += xs_b * wv.w;
            }
        }
    }

#pragma unroll
    for (int c = 0; c < 4; c++) {
        accA[c].x += __shfl_xor(accA[c].x, 1); accA[c].x += __shfl_xor(accA[c].x, 2);
        accA[c].y += __shfl_xor(accA[c].y, 1); accA[c].y += __shfl_xor(accA[c].y, 2);
        accA[c].z += __shfl_xor(accA[c].z, 1); accA[c].z += __shfl_xor(accA[c].z, 2);
        accA[c].w += __shfl_xor(accA[c].w, 1); accA[c].w += __shfl_xor(accA[c].w, 2);
        accB[c].x += __shfl_xor(accB[c].x, 1); accB[c].x += __shfl_xor(accB[c].x, 2);
        accB[c].y += __shfl_xor(accB[c].y, 1); accB[c].y += __shfl_xor(accB[c].y, 2);
        accB[c].z += __shfl_xor(accB[c].z, 1); accB[c].z += __shfl_xor(accB[c].z, 2);
        accB[c].w += __shfl_xor(accB[c].w, 1); accB[c].w += __shfl_xor(accB[c].w, 2);
    }

    __half* dstbuf = half ? m1hB : m1hA;
    {
        float4 a = accA[part];
        __half2 h01, h23;
        h01.x = __float2half_rn(a.x); h01.y = __float2half_rn(a.y);
        h23.x = __float2half_rn(a.z); h23.y = __float2half_rn(a.w);
        int2 pk; pk.x = *(int*)&h01; pk.y = *(int*)&h23;
        ((int2*)(dstbuf + (size_t)r0 * D_HID))[part] = pk;
    }
    if (has1) {
        float4 a = accB[part];
        __half2 h01, h23;
        h01.x = __float2half_rn(a.x); h01.y = __float2half_rn(a.y);
        h23.x = __float2half_rn(a.z); h23.y = __float2half_rn(a.w);
        int2 pk; pk.x = *(int*)&h01; pk.y = *(int*)&h23;
        ((int2*)(dstbuf + (size_t)r1 * D_HID))[part] = pk;
    }
}

// fused: per-bucket count + scan (rs) + dis + SUM K-halves + dis-scale m1h +
// counting-sort by dl. uint4-vectorized packed reads.
__global__ __launch_bounds__(512) void k_rssort(const unsigned int* __restrict__ packed,
                                                const int* __restrict__ gcur,
                                                int* __restrict__ rs,
                                                float* __restrict__ dis,
                                                __half* __restrict__ m1hA,
                                                const __half* __restrict__ m1hB,
                                                int* __restrict__ sorted, int n) {
    __shared__ int c[BKT], s[BKT], cur[BKT];
    int b = blockIdx.x, t = threadIdx.x;
    if (t < BKT) c[t] = 0;
    __syncthreads();
    int e0 = b * CAP;
    int cnt = gcur[b] - e0;
    int e1 = e0 + cnt;
    int nv = cnt >> 2;
    const uint4* p4 = (const uint4*)(packed + e0);
    for (int i = t; i < nv; i += 512) {
        uint4 v = p4[i];
        atomicAdd(&c[v.x & 255], 1);
        atomicAdd(&c[v.y & 255], 1);
        atomicAdd(&c[v.z & 255], 1);
        atomicAdd(&c[v.w & 255], 1);
    }
    for (int e = e0 + (nv << 2) + t; e < e1; e += 512)
        atomicAdd(&c[packed[e] & 255], 1);
    __syncthreads();
    int v = (t < BKT) ? c[t] : 0;
    if (t < BKT) s[t] = v;
    __syncthreads();
    for (int off = 1; off < BKT; off <<= 1) {
        int u = (t < BKT && t >= off) ? s[t - off] : 0;
        __syncthreads();
        if (t < BKT) s[t] += u;
        __syncthreads();
    }
    if (t < BKT) {
        int ex = s[t] - v;
        rs[b * 257 + t] = ex;
        cur[t] = ex;
        if (t == BKT - 1) rs[b * 257 + BKT] = s[t];
        int node = b * BKT + t;
        if (node < n) {
            float dv = rsqrtf((float)(v + 1));
            dis[node] = dv;
            int2* rowA = (int2*)(m1hA + (size_t)node * D_HID);
            const int2* rowB = (const int2*)(m1hB + (size_t)node * D_HID);
#pragma unroll
            for (int j = 0; j < 4; j++) {
                int2 pa = rowA[j];
                int2 pb = rowB[j];
                float2 a0 = __half22float2(*(__half2*)&pa.x);
                float2 a1 = __half22float2(*(__half2*)&pa.y);
                float2 b0 = __half22float2(*(__half2*)&pb.x);
                float2 b1 = __half22float2(*(__half2*)&pb.y);
                __half2 oa, ob;
                oa.x = __float2half_rn((a0.x + b0.x) * dv);
                oa.y = __float2half_rn((a0.y + b0.y) * dv);
                ob.x = __float2half_rn((a1.x + b1.x) * dv);
                ob.y = __float2half_rn((a1.y + b1.y) * dv);
                pa.x = *(int*)&oa; pa.y = *(int*)&ob;
                rowA[j] = pa;
            }
        }
    }
    __syncthreads();
    for (int i = t; i < nv; i += 512) {
        uint4 pv = p4[i];
#define SORT1(vv) { \
        int slot = atomicAdd(&cur[(vv) & 255], 1); \
        sorted[e0 + slot] = (int)((vv) >> 8); }
        SORT1(pv.x) SORT1(pv.y) SORT1(pv.z) SORT1(pv.w)
    }
    for (int e = e0 + (nv << 2) + t; e < e1; e += 512) {
        unsigned int pv = packed[e];
        SORT1(pv)
    }
#undef SORT1
}

// layer-1 aggregation: one 4-lane group per node, register accumulation,
// fused bias/relu/dis epilogue. out(fp16) = dis*relu(dis*(sum+self) + b1)
__global__ __launch_bounds__(256) void k_agg2(const int* __restrict__ sorted,
                                              const int* __restrict__ rs,
                                              const __half* __restrict__ msg,
                                              const float* __restrict__ dis,
                                              const float* __restrict__ b1,
                                              __half* __restrict__ outb, int n) {
    int b = blockIdx.x >> 2;
    int quarter = blockIdx.x & 3;
    int t = threadIdx.x;
    int q = t & 3, g = t >> 2;
    int dl = quarter * 64 + g;
    int node = b * BKT + dl;
    if (node >= n) return;

    const int2* msg2 = (const int2*)msg;

    int2 r = msg2[(size_t)node * 4 + q];
    float2 f0 = __half22float2(*(__half2*)&r.x);
    float2 f1 = __half22float2(*(__half2*)&r.y);
    float a0 = f0.x, a1 = f0.y, a2 = f1.x, a3 = f1.y;

    int base = b * CAP;
    int e  = base + rs[b * 257 + dl];
    int e1 = base + rs[b * 257 + dl + 1];

    for (; e + 3 < e1; e += 4) {
        int s0 = sorted[e + 0];
        int s1 = sorted[e + 1];
        int s2 = sorted[e + 2];
        int s3 = sorted[e + 3];
        int2 m0 = msg2[(size_t)s0 * 4 + q];
        int2 m1 = msg2[(size_t)s1 * 4 + q];
        int2 m2 = msg2[(size_t)s2 * 4 + q];
        int2 m3 = msg2[(size_t)s3 * 4 + q];
        float2 p0 = __half22float2(*(__half2*)&m0.x), p1 = __half22float2(*(__half2*)&m0.y);
        a0 += p0.x; a1 += p0.y; a2 += p1.x; a3 += p1.y;
        p0 = __half22float2(*(__half2*)&m1.x); p1 = __half22float2(*(__half2*)&m1.y);
        a0 += p0.x; a1 += p0.y; a2 += p1.x; a3 += p1.y;
        p0 = __half22float2(*(__half2*)&m2.x); p1 = __half22float2(*(__half2*)&m2.y);
        a0 += p0.x; a1 += p0.y; a2 += p1.x; a3 += p1.y;
        p0 = __half22float2(*(__half2*)&m3.x); p1 = __half22float2(*(__half2*)&m3.y);
        a0 += p0.x; a1 += p0.y; a2 += p1.x; a3 += p1.y;
    }
    for (; e < e1; e++) {
        int ssrc = sorted[e];
        int2 m0 = msg2[(size_t)ssrc * 4 + q];
        float2 p0 = __half22float2(*(__half2*)&m0.x), p1 = __half22float2(*(__half2*)&m0.y);
        a0 += p0.x; a1 += p0.y; a2 += p1.x; a3 += p1.y;
    }

    float di = dis[node];
    const float4 bb = ((const float4*)b1)[q];
    __half2 o01, o23;
    o01.x = __float2half_rn(di * fmaxf(di * a0 + bb.x, 0.0f));
    o01.y = __float2half_rn(di * fmaxf(di * a1 + bb.y, 0.0f));
    o23.x = __float2half_rn(di * fmaxf(di * a2 + bb.z, 0.0f));
    o23.y = __float2half_rn(di * fmaxf(di * a3 + bb.w, 0.0f));
    int2 pk;
    pk.x = *(int*)&o01; pk.y = *(int*)&o23;
    ((int2*)outb)[(size_t)node * 4 + q] = pk;
}

// fused layer-2 aggregation + W2 GEMV + log_softmax: one wave per node.
__global__ __launch_bounds__(256) void k_fin2(const int* __restrict__ sorted,
                                              const int* __restrict__ rs,
                                              const __half* __restrict__ msg,
                                              const float* __restrict__ dis,
                                              const float* __restrict__ W2,
                                              const float* __restrict__ b2,
                                              float* __restrict__ out, int n) {
    int lane = threadIdx.x & 63;
    int node = blockIdx.x * 4 + (threadIdx.x >> 6);
    if (node >= n) return;
    int b = node >> 8, dl = node & 255;
    int q = lane & 3, eg = lane >> 2;
    const int2* msg2 = (const int2*)msg;

    float a0 = 0.f, a1 = 0.f, a2 = 0.f, a3 = 0.f;
    if (eg == 0) {  // self-loop
        int2 r = msg2[(size_t)node * 4 + q];
        float2 f0 = __half22float2(*(__half2*)&r.x);
        float2 f1 = __half22float2(*(__half2*)&r.y);
        a0 = f0.x; a1 = f0.y; a2 = f1.x; a3 = f1.y;
    }
    int base = b * CAP;
    int s0 = rs[b * 257 + dl], s1 = rs[b * 257 + dl + 1];
    for (int i = s0 + eg; i < s1; i += 16) {
        int src = sorted[base + i];
        int2 m = msg2[(size_t)src * 4 + q];
        float2 p0 = __half22float2(*(__half2*)&m.x);
        float2 p1 = __half22float2(*(__half2*)&m.y);
        a0 += p0.x; a1 += p0.y; a2 += p1.x; a3 += p1.y;
    }
#pragma unroll
    for (int off = 4; off < 64; off <<= 1) {
        a0 += __shfl_xor(a0, off);
        a1 += __shfl_xor(a1, off);
        a2 += __shfl_xor(a2, off);
        a3 += __shfl_xor(a3, off);
    }
    float di = dis[node];
    a0 *= di; a1 *= di; a2 *= di; a3 *= di;

    int base4 = lane & ~3;
    float v = b2[lane];
#pragma unroll
    for (int c = 0; c < 4; c++) {
        float g0 = __shfl(a0, base4 + c);
        float g1 = __shfl(a1, base4 + c);
        float g2 = __shfl(a2, base4 + c);
        float g3 = __shfl(a3, base4 + c);
        v += g0 * W2[(c * 4 + 0) * D_OUT + lane];
        v += g1 * W2[(c * 4 + 1) * D_OUT + lane];
        v += g2 * W2[(c * 4 + 2) * D_OUT + lane];
        v += g3 * W2[(c * 4 + 3) * D_OUT + lane];
    }

    float mx = v;
#pragma unroll
    for (int off = 32; off; off >>= 1) mx = fmaxf(mx, __shfl_xor(mx, off));
    float ev = expf(v - mx);
    float sum = ev;
#pragma unroll
    for (int off = 32; off; off >>= 1) sum += __shfl_xor(sum, off);
    out[(size_t)node * D_OUT + lane] = (v - mx) - logf(sum);
}

// ---------------------------------------------------------------------------
#define ALIGN4(x) (((x) + 3) & ~(size_t)3)

extern "C" void kernel_launch(void* const* d_in, const int* in_sizes, int n_in,
                              void* d_out, int out_size, void* d_ws, size_t ws_size,
                              hipStream_t stream) {
    const float* x  = (const float*)d_in[0];
    const int*   ei = (const int*)d_in[1];
    const float* W1 = (const float*)d_in[2];
    const float* b1 = (const float*)d_in[3];
    const float* W2 = (const float*)d_in[4];
    const float* b2 = (const float*)d_in[5];
    float* out = (float*)d_out;

    int n = in_sizes[0] / D_IN;   // 100000
    int E = in_sizes[1] / 2;      // 3200000
    const int* src = ei;
    const int* dst = ei + E;
    int NB = (n + BKT - 1) / BKT; // 391

    size_t off = 0;               // offsets in 4-byte words, 16B-aligned blocks
    int* gcur   = (int*)d_ws + off;              off = ALIGN4(off + NB);
    int* rs     = (int*)d_ws + off;              off = ALIGN4(off + (size_t)NB * 257);
    unsigned int* packed = (unsigned int*)d_ws + off; off = ALIGN4(off + (size_t)NB * CAP);
    int* sorted = (int*)d_ws + off;              off = ALIGN4(off + (size_t)NB * CAP);
    float* dis  = (float*)((int*)d_ws + off);    off = ALIGN4(off + n);
    __half* bufAh = (__half*)((int*)d_ws + off); off = ALIGN4(off + (size_t)n * D_HID / 2);
    __half* bufBh = (__half*)((int*)d_ws + off); off = ALIGN4(off + (size_t)n * D_HID / 2);

    const int B = 256;
    int gemmBlocks = 2 * (int)((n + 127) / 128);    // 2 K-halves x 128-row tiles
    k_init   <<<1, 512, 0, stream>>>(gcur, NB);
    k_gp     <<<NBLK + gemmBlocks, B, 0, stream>>>(x, W1, src, dst, gcur, packed,
                                                   bufAh, bufBh, E, NB, n);
    k_rssort <<<NB, 512, 0, stream>>>(packed, gcur, rs, dis, bufAh, bufBh, sorted, n);
    k_agg2   <<<NB * 4, B, 0, stream>>>(sorted, rs, bufAh, dis, b1, bufBh, n);
    k_fin2   <<<(n + 3) / 4, B, 0, stream>>>(sorted, rs, bufBh, dis, W2, b2, out, n);
}

// Round 24
// 207.543 us; speedup vs baseline: 1.7838x; 1.7838x over previous
//
#include <hip/hip_runtime.h>
#include <hip/hip_fp16.h>
#include <math.h>

#define D_IN  512
#define D_HID 16
#define D_OUT 64
#define NBLK  256   // partition chunks
#define BKT   256   // nodes per bucket
#define CAP   12288 // fixed edge capacity per bucket (mean 8192, sigma~90)

// ---------------------------------------------------------------------------
// init global bucket cursors: gcur[b] = b*CAP
__global__ __launch_bounds__(512) void k_init(int* __restrict__ gcur, int NB) {
    int i = threadIdx.x;
    if (i < NB) gcur[i] = i * CAP;
}

// fused partition + gemm1 in ONE dispatch (independent halves overlap):
//  blocks [0, NBLK)   : edge partition (LDS histogram -> one global
//                       atomicAdd per (block,bucket) -> scatter packed)
//  blocks [NBLK, ...) : m1h[r][j] = fp16( sum_k x[r][k] * W1[k][j] ), UNSCALED
// gemm = validated v4 (round 15/18/21, reproduced 4x at 207.6-207.9us total):
// one row per 4-lane group, unroll 8, W1 in LDS f32 float4, XOR swizzle
// [k][c ^ ((k>>7)&3)] read as [kk][c ^ part] (disjoint bank quads; 0
// conflicts). 44 VGPR, no spill. SEVEN variants tried and falsified:
// fp16-LDS pinned/unpinned (r16,r17), no-LDS (r19), min-waves+batch (r20),
// split-K 1-row (r22), split-K 2-row (r23: L2-locality fetch explosion).
__global__ __launch_bounds__(256) void k_gp(const float* __restrict__ x,
                                            const float* __restrict__ W1,
                                            const int* __restrict__ src,
                                            const int* __restrict__ dst,
                                            int* __restrict__ gcur,
                                            unsigned int* __restrict__ packed,
                                            __half* __restrict__ m1h,
                                            int E, int NB, int n) {
    __shared__ float4 w4s[D_IN][4];  // 32 KiB (partition path aliases 4 KiB)
    int t = threadIdx.x;

    if (blockIdx.x < NBLK) {
        // ---------------- partition path ----------------
        int* h   = (int*)&w4s[0][0];
        int* cur = h + 512;
        for (int i = t; i < NB; i += 256) h[i] = 0;
        __syncthreads();
        int per = (E + NBLK - 1) / NBLK;
        int e0 = blockIdx.x * per, e1 = min(E, e0 + per);
        int nv = (e1 - e0) >> 2;
        const int4* d4 = (const int4*)(dst + e0);
        for (int i = t; i < nv; i += 256) {
            int4 v = d4[i];
            atomicAdd(&h[v.x >> 8], 1);
            atomicAdd(&h[v.y >> 8], 1);
            atomicAdd(&h[v.z >> 8], 1);
            atomicAdd(&h[v.w >> 8], 1);
        }
        for (int e = e0 + (nv << 2) + t; e < e1; e += 256)
            atomicAdd(&h[dst[e] >> 8], 1);
        __syncthreads();
        for (int i = t; i < NB; i += 256) {
            int c = h[i];
            cur[i] = c ? atomicAdd(&gcur[i], c) : 0;
        }
        __syncthreads();
        const int4* s4 = (const int4*)(src + e0);
        for (int i = t; i < nv; i += 256) {
            int4 sv = s4[i];
            int4 dv = d4[i];
#define PUT(ss, dd) { \
            int slot = atomicAdd(&cur[(dd) >> 8], 1); \
            packed[slot] = ((unsigned int)(ss) << 8) | (unsigned int)((dd) & 255); }
            PUT(sv.x, dv.x) PUT(sv.y, dv.y) PUT(sv.z, dv.z) PUT(sv.w, dv.w)
        }
        for (int e = e0 + (nv << 2) + t; e < e1; e += 256) {
            int d = dst[e];
            PUT(src[e], d)
        }
#undef PUT
        return;
    }

    // ---------------- gemm path ----------------
    const float4* W14 = (const float4*)W1;
    for (int i = t; i < D_IN * 4; i += 256) {
        int k = i >> 2, c = i & 3;
        w4s[k][c ^ ((k >> 7) & 3)] = W14[i];
    }
    __syncthreads();

    int gid  = (blockIdx.x - NBLK) * 256 + t;
    int row  = gid >> 2;
    int part = gid & 3;
    if (row >= n) return;

    const float4* xr = (const float4*)(x + (size_t)row * D_IN) + part * 32;

    float4 acc[4];
#pragma unroll
    for (int c = 0; c < 4; c++) acc[c] = make_float4(0.f, 0.f, 0.f, 0.f);

#pragma unroll 8
    for (int m = 0; m < 32; m++) {
        float4 xa = xr[m];
        int kb = part * 128 + m * 4;
#pragma unroll
        for (int u = 0; u < 4; u++) {
            int kk = kb + u;
            float xs = (u == 0) ? xa.x : (u == 1) ? xa.y : (u == 2) ? xa.z : xa.w;
#pragma unroll
            for (int c = 0; c < 4; c++) {
                float4 wv = w4s[kk][c ^ part];
                acc[c].x += xs * wv.x; acc[c].y += xs * wv.y;
                acc[c].z += xs * wv.z; acc[c].w += xs * wv.w;
            }
        }
    }

#pragma unroll
    for (int c = 0; c < 4; c++) {
        acc[c].x += __shfl_xor(acc[c].x, 1); acc[c].x += __shfl_xor(acc[c].x, 2);
        acc[c].y += __shfl_xor(acc[c].y, 1); acc[c].y += __shfl_xor(acc[c].y, 2);
        acc[c].z += __shfl_xor(acc[c].z, 1); acc[c].z += __shfl_xor(acc[c].z, 2);
        acc[c].w += __shfl_xor(acc[c].w, 1); acc[c].w += __shfl_xor(acc[c].w, 2);
    }

    float4 a = acc[part];   // UNSCALED m1 (dis applied in k_rssort)
    __half2 h01, h23;
    h01.x = __float2half_rn(a.x); h01.y = __float2half_rn(a.y);
    h23.x = __float2half_rn(a.z); h23.y = __float2half_rn(a.w);
    int2 pk; pk.x = *(int*)&h01; pk.y = *(int*)&h23;
    ((int2*)(m1h + (size_t)row * D_HID))[part] = pk;
}

// fused: per-bucket count + exclusive scan (rs) + dis + m1h dis-scaling +
// counting-sort by dl. uint4-vectorized packed reads.
__global__ __launch_bounds__(512) void k_rssort(const unsigned int* __restrict__ packed,
                                                const int* __restrict__ gcur,
                                                int* __restrict__ rs,
                                                float* __restrict__ dis,
                                                __half* __restrict__ m1h,
                                                int* __restrict__ sorted, int n) {
    __shared__ int c[BKT], s[BKT], cur[BKT];
    int b = blockIdx.x, t = threadIdx.x;
    if (t < BKT) c[t] = 0;
    __syncthreads();
    int e0 = b * CAP;
    int cnt = gcur[b] - e0;
    int e1 = e0 + cnt;
    int nv = cnt >> 2;
    const uint4* p4 = (const uint4*)(packed + e0);
    for (int i = t; i < nv; i += 512) {
        uint4 v = p4[i];
        atomicAdd(&c[v.x & 255], 1);
        atomicAdd(&c[v.y & 255], 1);
        atomicAdd(&c[v.z & 255], 1);
        atomicAdd(&c[v.w & 255], 1);
    }
    for (int e = e0 + (nv << 2) + t; e < e1; e += 512)
        atomicAdd(&c[packed[e] & 255], 1);
    __syncthreads();
    int v = (t < BKT) ? c[t] : 0;
    if (t < BKT) s[t] = v;
    __syncthreads();
    for (int off = 1; off < BKT; off <<= 1) {
        int u = (t < BKT && t >= off) ? s[t - off] : 0;
        __syncthreads();
        if (t < BKT) s[t] += u;
        __syncthreads();
    }
    if (t < BKT) {
        int ex = s[t] - v;
        rs[b * 257 + t] = ex;
        cur[t] = ex;
        if (t == BKT - 1) rs[b * 257 + BKT] = s[t];
        int node = b * BKT + t;
        if (node < n) {
            float dv = rsqrtf((float)(v + 1));
            dis[node] = dv;
            int2* rowp = (int2*)(m1h + (size_t)node * D_HID);
#pragma unroll
            for (int j = 0; j < 4; j++) {
                int2 pk = rowp[j];
                float2 fa = __half22float2(*(__half2*)&pk.x);
                float2 fb = __half22float2(*(__half2*)&pk.y);
                __half2 oa, ob;
                oa.x = __float2half_rn(fa.x * dv); oa.y = __float2half_rn(fa.y * dv);
                ob.x = __float2half_rn(fb.x * dv); ob.y = __float2half_rn(fb.y * dv);
                pk.x = *(int*)&oa; pk.y = *(int*)&ob;
                rowp[j] = pk;
            }
        }
    }
    __syncthreads();
    for (int i = t; i < nv; i += 512) {
        uint4 pv = p4[i];
#define SORT1(vv) { \
        int slot = atomicAdd(&cur[(vv) & 255], 1); \
        sorted[e0 + slot] = (int)((vv) >> 8); }
        SORT1(pv.x) SORT1(pv.y) SORT1(pv.z) SORT1(pv.w)
    }
    for (int e = e0 + (nv << 2) + t; e < e1; e += 512) {
        unsigned int pv = packed[e];
        SORT1(pv)
    }
#undef SORT1
}

// layer-1 aggregation: one 4-lane group per node, register accumulation,
// fused bias/relu/dis epilogue. out(fp16) = dis*relu(dis*(sum+self) + b1)
__global__ __launch_bounds__(256) void k_agg2(const int* __restrict__ sorted,
                                              const int* __restrict__ rs,
                                              const __half* __restrict__ msg,
                                              const float* __restrict__ dis,
                                              const float* __restrict__ b1,
                                              __half* __restrict__ outb, int n) {
    int b = blockIdx.x >> 2;
    int quarter = blockIdx.x & 3;
    int t = threadIdx.x;
    int q = t & 3, g = t >> 2;
    int dl = quarter * 64 + g;
    int node = b * BKT + dl;
    if (node >= n) return;

    const int2* msg2 = (const int2*)msg;

    int2 r = msg2[(size_t)node * 4 + q];
    float2 f0 = __half22float2(*(__half2*)&r.x);
    float2 f1 = __half22float2(*(__half2*)&r.y);
    float a0 = f0.x, a1 = f0.y, a2 = f1.x, a3 = f1.y;

    int base = b * CAP;
    int e  = base + rs[b * 257 + dl];
    int e1 = base + rs[b * 257 + dl + 1];

    for (; e + 3 < e1; e += 4) {
        int s0 = sorted[e + 0];
        int s1 = sorted[e + 1];
        int s2 = sorted[e + 2];
        int s3 = sorted[e + 3];
        int2 m0 = msg2[(size_t)s0 * 4 + q];
        int2 m1 = msg2[(size_t)s1 * 4 + q];
        int2 m2 = msg2[(size_t)s2 * 4 + q];
        int2 m3 = msg2[(size_t)s3 * 4 + q];
        float2 p0 = __half22float2(*(__half2*)&m0.x), p1 = __half22float2(*(__half2*)&m0.y);
        a0 += p0.x; a1 += p0.y; a2 += p1.x; a3 += p1.y;
        p0 = __half22float2(*(__half2*)&m1.x); p1 = __half22float2(*(__half2*)&m1.y);
        a0 += p0.x; a1 += p0.y; a2 += p1.x; a3 += p1.y;
        p0 = __half22float2(*(__half2*)&m2.x); p1 = __half22float2(*(__half2*)&m2.y);
        a0 += p0.x; a1 += p0.y; a2 += p1.x; a3 += p1.y;
        p0 = __half22float2(*(__half2*)&m3.x); p1 = __half22float2(*(__half2*)&m3.y);
        a0 += p0.x; a1 += p0.y; a2 += p1.x; a3 += p1.y;
    }
    for (; e < e1; e++) {
        int ssrc = sorted[e];
        int2 m0 = msg2[(size_t)ssrc * 4 + q];
        float2 p0 = __half22float2(*(__half2*)&m0.x), p1 = __half22float2(*(__half2*)&m0.y);
        a0 += p0.x; a1 += p0.y; a2 += p1.x; a3 += p1.y;
    }

    float di = dis[node];
    const float4 bb = ((const float4*)b1)[q];
    __half2 o01, o23;
    o01.x = __float2half_rn(di * fmaxf(di * a0 + bb.x, 0.0f));
    o01.y = __float2half_rn(di * fmaxf(di * a1 + bb.y, 0.0f));
    o23.x = __float2half_rn(di * fmaxf(di * a2 + bb.z, 0.0f));
    o23.y = __float2half_rn(di * fmaxf(di * a3 + bb.w, 0.0f));
    int2 pk;
    pk.x = *(int*)&o01; pk.y = *(int*)&o23;
    ((int2*)outb)[(size_t)node * 4 + q] = pk;
}

// fused layer-2 aggregation + W2 GEMV + log_softmax: one wave per node.
// lane = eg*4 + q: 16 edge-groups x 4 column-lanes; butterfly over eg,
// then shfl-gather the 16 g values and do the GEMV per output lane.
__global__ __launch_bounds__(256) void k_fin2(const int* __restrict__ sorted,
                                              const int* __restrict__ rs,
                                              const __half* __restrict__ msg,
                                              const float* __restrict__ dis,
                                              const float* __restrict__ W2,
                                              const float* __restrict__ b2,
                                              float* __restrict__ out, int n) {
    int lane = threadIdx.x & 63;
    int node = blockIdx.x * 4 + (threadIdx.x >> 6);
    if (node >= n) return;
    int b = node >> 8, dl = node & 255;
    int q = lane & 3, eg = lane >> 2;
    const int2* msg2 = (const int2*)msg;

    float a0 = 0.f, a1 = 0.f, a2 = 0.f, a3 = 0.f;
    if (eg == 0) {  // self-loop
        int2 r = msg2[(size_t)node * 4 + q];
        float2 f0 = __half22float2(*(__half2*)&r.x);
        float2 f1 = __half22float2(*(__half2*)&r.y);
        a0 = f0.x; a1 = f0.y; a2 = f1.x; a3 = f1.y;
    }
    int base = b * CAP;
    int s0 = rs[b * 257 + dl], s1 = rs[b * 257 + dl + 1];
    for (int i = s0 + eg; i < s1; i += 16) {
        int src = sorted[base + i];
        int2 m = msg2[(size_t)src * 4 + q];
        float2 p0 = __half22float2(*(__half2*)&m.x);
        float2 p1 = __half22float2(*(__half2*)&m.y);
        a0 += p0.x; a1 += p0.y; a2 += p1.x; a3 += p1.y;
    }
#pragma unroll
    for (int off = 4; off < 64; off <<= 1) {
        a0 += __shfl_xor(a0, off);
        a1 += __shfl_xor(a1, off);
        a2 += __shfl_xor(a2, off);
        a3 += __shfl_xor(a3, off);
    }
    float di = dis[node];
    a0 *= di; a1 *= di; a2 *= di; a3 *= di;

    int base4 = lane & ~3;
    float v = b2[lane];
#pragma unroll
    for (int c = 0; c < 4; c++) {
        float g0 = __shfl(a0, base4 + c);
        float g1 = __shfl(a1, base4 + c);
        float g2 = __shfl(a2, base4 + c);
        float g3 = __shfl(a3, base4 + c);
        v += g0 * W2[(c * 4 + 0) * D_OUT + lane];
        v += g1 * W2[(c * 4 + 1) * D_OUT + lane];
        v += g2 * W2[(c * 4 + 2) * D_OUT + lane];
        v += g3 * W2[(c * 4 + 3) * D_OUT + lane];
    }

    float mx = v;
#pragma unroll
    for (int off = 32; off; off >>= 1) mx = fmaxf(mx, __shfl_xor(mx, off));
    float ev = expf(v - mx);
    float sum = ev;
#pragma unroll
    for (int off = 32; off; off >>= 1) sum += __shfl_xor(sum, off);
    out[(size_t)node * D_OUT + lane] = (v - mx) - logf(sum);
}

// ---------------------------------------------------------------------------
#define ALIGN4(x) (((x) + 3) & ~(size_t)3)

extern "C" void kernel_launch(void* const* d_in, const int* in_sizes, int n_in,
                              void* d_out, int out_size, void* d_ws, size_t ws_size,
                              hipStream_t stream) {
    const float* x  = (const float*)d_in[0];
    const int*   ei = (const int*)d_in[1];
    const float* W1 = (const float*)d_in[2];
    const float* b1 = (const float*)d_in[3];
    const float* W2 = (const float*)d_in[4];
    const float* b2 = (const float*)d_in[5];
    float* out = (float*)d_out;

    int n = in_sizes[0] / D_IN;   // 100000
    int E = in_sizes[1] / 2;      // 3200000
    const int* src = ei;
    const int* dst = ei + E;
    int NB = (n + BKT - 1) / BKT; // 391

    size_t off = 0;               // offsets in 4-byte words, 16B-aligned blocks
    int* gcur   = (int*)d_ws + off;              off = ALIGN4(off + NB);
    int* rs     = (int*)d_ws + off;              off = ALIGN4(off + (size_t)NB * 257);
    unsigned int* packed = (unsigned int*)d_ws + off; off = ALIGN4(off + (size_t)NB * CAP);
    int* sorted = (int*)d_ws + off;              off = ALIGN4(off + (size_t)NB * CAP);
    float* dis  = (float*)((int*)d_ws + off);    off = ALIGN4(off + n);
    __half* bufAh = (__half*)((int*)d_ws + off); off = ALIGN4(off + (size_t)n * D_HID / 2);
    __half* bufBh = (__half*)((int*)d_ws + off); off = ALIGN4(off + (size_t)n * D_HID / 2);

    const int B = 256;
    int gemmBlocks = ((size_t)n * 4 + B - 1) / B;   // 1563
    k_init   <<<1, 512, 0, stream>>>(gcur, NB);
    k_gp     <<<NBLK + gemmBlocks, B, 0, stream>>>(x, W1, src, dst, gcur, packed,
                                                   bufAh, E, NB, n);
    k_rssort <<<NB, 512, 0, stream>>>(packed, gcur, rs, dis, bufAh, sorted, n);
    k_agg2   <<<NB * 4, B, 0, stream>>>(sorted, rs, bufAh, dis, b1, bufBh, n);
    k_fin2   <<<(n + 3) / 4, B, 0, stream>>>(sorted, rs, bufBh, dis, W2, b2, out, n);
}